// Round 5
// baseline (1398.839 us; speedup 1.0000x reference)
//
#include <hip/hip_runtime.h>

#define N_ 10000
#define H_ 4
#define F_ 128
#define HF_ 512
#define E_ 320000
#define EN_ 330000  // E + N self loops

typedef unsigned short u16;
typedef __attribute__((ext_vector_type(8))) short bf16x8;
typedef __attribute__((ext_vector_type(4))) float f32x4;

__device__ __forceinline__ u16 f2b1(float f) {
  return (u16)((__float_as_uint(f) + 0x8000u) >> 16);
}
__device__ __forceinline__ unsigned int f2b2(float a, float b) {
  unsigned int ua = __float_as_uint(a) + 0x8000u;
  unsigned int ub = __float_as_uint(b) + 0x8000u;
  return (ua >> 16) | (ub & 0xffff0000u);
}
__device__ __forceinline__ float b2f(u16 u) {
  return __uint_as_float(((unsigned int)u) << 16);
}
__device__ __forceinline__ void async_cp16(const void* g, void* l) {
  __builtin_amdgcn_global_load_lds((__attribute__((address_space(1))) void*)g,
                                   (__attribute__((address_space(3))) void*)l,
                                   16, 0, 0);
}

// ---------------- transpose + convert: out_bf16[c][r] = in_f32[r][c] ----------------
__global__ void transpose_f2b(const float* __restrict__ in, u16* __restrict__ out,
                              int R, int C) {
  __shared__ float t[32][33];
  int bx = blockIdx.x * 32, by = blockIdx.y * 32;
  int tx = threadIdx.x, ty = threadIdx.y;  // 32 x 8
#pragma unroll
  for (int i = 0; i < 32; i += 8) {
    int r = by + ty + i, c = bx + tx;
    if (r < R && c < C) t[ty + i][tx] = in[(size_t)r * C + c];
  }
  __syncthreads();
#pragma unroll
  for (int i = 0; i < 32; i += 8) {
    int c = bx + ty + i, r = by + tx;
    if (r < R && c < C) out[(size_t)c * R + r] = f2b1(t[tx][ty + i]);
  }
}

// ---------------- CSR build ----------------
__global__ void zero_k(int* __restrict__ p, int n) {
  int t = blockIdx.x * blockDim.x + threadIdx.x;
  if (t < n) p[t] = 0;
}
__global__ void hist_k(const int* __restrict__ ei, int* __restrict__ cnt) {
  int t = blockIdx.x * blockDim.x + threadIdx.x;
  if (t >= EN_) return;
  int d = (t < E_) ? ei[E_ + t] : (t - E_);
  atomicAdd(&cnt[d], 1);
}
__global__ void scan_k(const int* __restrict__ cnt, int* __restrict__ rp) {
  __shared__ int l[1024];
  const int CH = 10;
  int t = threadIdx.x;
  int base = t * CH;
  int loc[CH];
  int s = 0;
#pragma unroll
  for (int i = 0; i < CH; ++i) {
    int idx = base + i;
    int c = (idx < N_) ? cnt[idx] : 0;
    loc[i] = s; s += c;
  }
  l[t] = s;
  __syncthreads();
  for (int off = 1; off < 1024; off <<= 1) {
    int v = (t >= off) ? l[t - off] : 0;
    __syncthreads();
    l[t] += v;
    __syncthreads();
  }
  int cb = (t == 0) ? 0 : l[t - 1];
#pragma unroll
  for (int i = 0; i < CH; ++i) {
    int idx = base + i;
    if (idx < N_) rp[idx] = cb + loc[i];
  }
  if (t == 1023) rp[N_] = l[1023];
}
__global__ void fill_k(const int* __restrict__ ei, const int* __restrict__ rp,
                       int* __restrict__ fl, int* __restrict__ csrc) {
  int t = blockIdx.x * blockDim.x + threadIdx.x;
  if (t >= EN_) return;
  int s, d;
  if (t < E_) { s = ei[t]; d = ei[E_ + t]; } else { s = d = t - E_; }
  int pos = rp[d] + atomicAdd(&fl[d], 1);
  csrc[pos] = s;
}

// ---------------- MFMA GEMM: C[M,Nc] = A[M,K] * Bt[Nc,K]^T ----------------
// BK=64 K-step: half the barriers of BK=32, 32 MFMA/wave per step.
// LDS tiles are [128 rows][64 cols] bf16 (128-B row stride) with a T2 XOR
// swizzle on the 16-B chunk index: chunk' = chunk ^ (row & 7). Writes via
// global_load_lds stay LINEAR in LDS (HW requirement); the swizzle is applied
// by permuting the per-lane GLOBAL source chunk (m173 pattern). Manual
// (fp32-convert) writes and all ds_reads apply the same XOR.
// ASRC 0: A is bf16 (async). ASRC 1: A is fp32 (fused convert staging).
// MODE 1 (non-split): sigmoid store. SPLIT 1: K-slices, z = flat%8 pins each
// K-slice to one XCD (A-panel L2 reuse; FETCH 830->240 MB measured).
#define MFMA_STEP(ASP, BSP)                                                   \
  {                                                                           \
    _Pragma("unroll") for (int ks = 0; ks < 2; ++ks) {                        \
      bf16x8 af[4], bv[4];                                                    \
      _Pragma("unroll") for (int i = 0; i < 4; ++i) {                         \
        int ra = wm + i * 16 + l16;                                           \
        af[i] = *(const bf16x8*)&(ASP)[ra * 64 +                              \
                                       (((ks * 4 + quad) ^ (ra & 7)) * 8)];   \
      }                                                                       \
      _Pragma("unroll") for (int j = 0; j < 4; ++j) {                         \
        int rb = wn + j * 16 + l16;                                           \
        bv[j] = *(const bf16x8*)&(BSP)[rb * 64 +                              \
                                       (((ks * 4 + quad) ^ (rb & 7)) * 8)];   \
      }                                                                       \
      _Pragma("unroll") for (int i = 0; i < 4; ++i)                           \
          _Pragma("unroll") for (int j = 0; j < 4; ++j)                       \
              acc[i][j] = __builtin_amdgcn_mfma_f32_16x16x32_bf16(            \
                  af[i], bv[j], acc[i][j], 0, 0, 0);                          \
    }                                                                         \
  }

template <int ASRC, int MODE, int SPLIT>
__global__ __launch_bounds__(256) void gemm_k(const void* __restrict__ Av,
                                              const u16* __restrict__ Bt,
                                              float* __restrict__ C,
                                              int M, int Nc, int K) {
  __shared__ u16 As[128 * 64];
  __shared__ u16 Bs[128 * 64];
  const int tid = threadIdx.x;
  const int lane = tid & 63, wave = tid >> 6;
  const int wm = (wave >> 1) * 64, wn = (wave & 1) * 64;
  const int l16 = lane & 15, quad = lane >> 4;

  int xb = blockIdx.x, yb = blockIdx.y, zb = 0;
  if (SPLIT) {
    int flat = blockIdx.x + gridDim.x * (blockIdx.y + gridDim.y * blockIdx.z);
    zb = flat % (int)gridDim.z;
    int r = flat / (int)gridDim.z;
    xb = r % (int)gridDim.x;
    yb = r / (int)gridDim.x;
  }
  const int mBase = yb * 128, nBase = xb * 128;

  int k0 = 0, k1 = K;
  if (SPLIT) {
    int Kper = ((K + (int)gridDim.z - 1) / (int)gridDim.z + 63) & ~63;
    k0 = zb * Kper;
    k1 = min(K, k0 + Kper);
    if (k0 > k1) k0 = k1;
  }
  const int len = k1 - k0;

  const u16* Ab = (const u16*)Av;
  const float* Af = (const float*)Av;

  // Async staging geometry: cp c (0..3) per lane covers (row, 8-col chunk)
  //   slot = c*64+lane; row = wave*32 + (slot>>3); chunk = slot&7
  //   global col chunk is XOR-swizzled; LDS dest stays linear (lane*16B).
  const u16* pB[4];
  const u16* pA[4];
  u16* dB[4];
  u16* dA[4];
#pragma unroll
  for (int c = 0; c < 4; ++c) {
    int slot = c * 64 + lane;
    int rl = wave * 32 + (slot >> 3);
    int ch = slot & 7;
    int gcol = ((ch ^ (rl & 7)) * 8);
    size_t gb = (size_t)min(nBase + rl, Nc - 1);
    pB[c] = Bt + gb * (size_t)K + k0 + gcol;
    dB[c] = Bs + wave * 2048 + c * 512;
    if (ASRC == 0) {
      size_t ga = (size_t)min(mBase + rl, M - 1);
      pA[c] = Ab + ga * (size_t)K + k0 + gcol;
      dA[c] = As + wave * 2048 + c * 512;
    }
  }
  // fp32-convert A geometry: thread covers row (tid>>1), 32 cols half.
  const int arow = tid >> 1, ahalf = (tid & 1) * 32;
  size_t agr = (size_t)min(mBase + arow, M - 1);
  const float* pfA = Af + agr * (size_t)K + k0 + ahalf;

  f32x4 acc[4][4];
  f32x4 zr = {0.f, 0.f, 0.f, 0.f};
#pragma unroll
  for (int i = 0; i < 4; ++i)
#pragma unroll
    for (int j = 0; j < 4; ++j) acc[i][j] = zr;

  const int Lmain = len & ~63;
  for (int kb = 0; kb < Lmain; kb += 64) {
#pragma unroll
    for (int c = 0; c < 4; ++c) {
      async_cp16(pB[c] + kb, dB[c]);
      if (ASRC == 0) async_cp16(pA[c] + kb, dA[c]);
    }
    if (ASRC == 1) {
      float4 xv[8];
#pragma unroll
      for (int j = 0; j < 8; ++j) xv[j] = *(const float4*)(pfA + kb + j * 4);
#pragma unroll
      for (int j = 0; j < 4; ++j) {
        uint4 u = make_uint4(
            f2b2(xv[2 * j].x, xv[2 * j].y), f2b2(xv[2 * j].z, xv[2 * j].w),
            f2b2(xv[2 * j + 1].x, xv[2 * j + 1].y),
            f2b2(xv[2 * j + 1].z, xv[2 * j + 1].w));
        int ch = (tid & 1) * 4 + j;
        *(uint4*)&As[arow * 64 + ((ch ^ (arow & 7)) * 8)] = u;
      }
    }
    __syncthreads();
    MFMA_STEP(As, Bs);
    __syncthreads();
  }

  if (len & 63) {  // tail < 64 K: zero-padded scalar stage (swizzled)
    int trow = tid >> 1, thalf = (tid & 1) * 32;
    size_t gra = (size_t)min(mBase + trow, M - 1);
    size_t grb = (size_t)min(nBase + trow, Nc - 1);
#pragma unroll
    for (int cc = 0; cc < 32; ++cc) {
      int col = thalf + cc;
      int k = k0 + Lmain + col;
      u16 av = 0, bvv = 0;
      if (k < k1) {
        av = (ASRC == 1) ? f2b1(Af[gra * (size_t)K + k]) : Ab[gra * (size_t)K + k];
        bvv = Bt[grb * (size_t)K + k];
      }
      int off = trow * 64 + (((col >> 3) ^ (trow & 7)) * 8) + (col & 7);
      As[off] = av;
      Bs[off] = bvv;
    }
    __syncthreads();
    MFMA_STEP(As, Bs);
  }

  float* Cw = SPLIT ? (C + (size_t)zb * (size_t)M * (size_t)Nc) : C;
#pragma unroll
  for (int i = 0; i < 4; ++i)
#pragma unroll
    for (int j = 0; j < 4; ++j)
#pragma unroll
      for (int r = 0; r < 4; ++r) {
        int row = mBase + wm + i * 16 + quad * 4 + r;
        int col = nBase + wn + j * 16 + l16;
        if (row < M && col < Nc) {
          float v = acc[i][j][r];
          if (!SPLIT && MODE == 1) v = 1.f / (1.f + __expf(-v));
          Cw[(size_t)row * Nc + col] = v;
        }
      }
}

// ---------------- prep: h fp32 (sum of S partials) -> h bf16, attention logits ----------------
__global__ __launch_bounds__(256) void prep_k(const float* __restrict__ h,
                                              const float* __restrict__ asv,
                                              const float* __restrict__ adv,
                                              u16* __restrict__ h2,
                                              float* __restrict__ als,
                                              float* __restrict__ ald,
                                              int S, size_t zstride) {
  int wave = threadIdx.x >> 6, lane = threadIdx.x & 63;
  int node = blockIdx.x * 4 + wave;
  if (node >= N_) return;
  const float* hp = h + (size_t)node * HF_;
  float4 v0 = ((const float4*)hp)[lane * 2];
  float4 v1 = ((const float4*)hp)[lane * 2 + 1];
#pragma unroll 1
  for (int z = 1; z < S; ++z) {
    const float* pp = hp + (size_t)z * zstride;
    float4 w0 = ((const float4*)pp)[lane * 2];
    float4 w1 = ((const float4*)pp)[lane * 2 + 1];
    v0.x += w0.x; v0.y += w0.y; v0.z += w0.z; v0.w += w0.w;
    v1.x += w1.x; v1.y += w1.y; v1.z += w1.z; v1.w += w1.w;
  }
  float vv[8] = {v0.x, v0.y, v0.z, v0.w, v1.x, v1.y, v1.z, v1.w};
  uint4 pk = make_uint4(f2b2(vv[0], vv[1]), f2b2(vv[2], vv[3]),
                        f2b2(vv[4], vv[5]), f2b2(vv[6], vv[7]));
  *(uint4*)&h2[(size_t)node * HF_ + lane * 8] = pk;
  float4 a0 = ((const float4*)(asv + lane * 8))[0];
  float4 a1 = ((const float4*)(asv + lane * 8))[1];
  float4 d0 = ((const float4*)(adv + lane * 8))[0];
  float4 d1 = ((const float4*)(adv + lane * 8))[1];
  float aa[8] = {a0.x, a0.y, a0.z, a0.w, a1.x, a1.y, a1.z, a1.w};
  float dd[8] = {d0.x, d0.y, d0.z, d0.w, d1.x, d1.y, d1.z, d1.w};
  float ss = 0.f, sd = 0.f;
#pragma unroll
  for (int j = 0; j < 8; ++j) {
    ss += vv[j] * aa[j];
    sd += vv[j] * dd[j];
  }
#pragma unroll
  for (int m = 1; m <= 8; m <<= 1) {
    ss += __shfl_xor(ss, m, 64);
    sd += __shfl_xor(sd, m, 64);
  }
  if ((lane & 15) == 0) {
    int hh = lane >> 4;
    als[node * 4 + hh] = ss;
    ald[node * 4 + hh] = sd;
  }
}

// ---------------- aggregate: per-dst softmax attention + head-mean + act ----------------
__global__ __launch_bounds__(256) void agg_k(const u16* __restrict__ h2,
                                             const float* __restrict__ als,
                                             const float* __restrict__ ald,
                                             const int* __restrict__ rp,
                                             const int* __restrict__ csrc,
                                             const float* __restrict__ bias,
                                             u16* __restrict__ xout,
                                             float* __restrict__ z32, int act) {
  __shared__ float red[1024];
  __shared__ float sh[512];
  int n = blockIdx.x, t = threadIdx.x;
  int start = rp[n], end = rp[n + 1];
  int hh = t >> 6;  // head of elements 2t, 2t+1
  float4 ad4 = *(const float4*)&ald[n * 4];
  float adh[4] = {ad4.x, ad4.y, ad4.z, ad4.w};
  float lm[4] = {-1e30f, -1e30f, -1e30f, -1e30f};
  for (int j = start + t; j < end; j += 256) {
    int s = csrc[j];
    float4 a4 = *(const float4*)&als[s * 4];
    float e0 = a4.x + adh[0]; e0 = e0 > 0.f ? e0 : 0.2f * e0;
    float e1 = a4.y + adh[1]; e1 = e1 > 0.f ? e1 : 0.2f * e1;
    float e2 = a4.z + adh[2]; e2 = e2 > 0.f ? e2 : 0.2f * e2;
    float e3 = a4.w + adh[3]; e3 = e3 > 0.f ? e3 : 0.2f * e3;
    lm[0] = fmaxf(lm[0], e0); lm[1] = fmaxf(lm[1], e1);
    lm[2] = fmaxf(lm[2], e2); lm[3] = fmaxf(lm[3], e3);
  }
#pragma unroll
  for (int h = 0; h < 4; ++h) red[t * 4 + h] = lm[h];
  __syncthreads();
  for (int off = 128; off >= 1; off >>= 1) {
    if (t < off) {
#pragma unroll
      for (int h = 0; h < 4; ++h)
        red[t * 4 + h] = fmaxf(red[t * 4 + h], red[(t + off) * 4 + h]);
    }
    __syncthreads();
  }
  float mh = red[hh];
  float adhh = adh[hh];
  float acc0 = 0.f, acc1 = 0.f, ssum = 0.f;
  for (int j = start; j < end; ++j) {
    int s = csrc[j];
    float e = als[s * 4 + hh] + adhh;
    e = e > 0.f ? e : 0.2f * e;
    float w = __expf(e - mh);
    ssum += w;
    unsigned int p = *(const unsigned int*)&h2[(size_t)s * HF_ + 2 * t];
    acc0 += w * b2f((u16)(p & 0xffffu));
    acc1 += w * b2f((u16)(p >> 16));
  }
  float inv = 1.f / ssum;
  sh[2 * t] = acc0 * inv;
  sh[2 * t + 1] = acc1 * inv;
  __syncthreads();
  if (t < 64) {
    int f0 = 2 * t, f1 = 2 * t + 1;
    float w0 = 0.25f * (sh[f0] + sh[128 + f0] + sh[256 + f0] + sh[384 + f0]) + bias[f0];
    float w1 = 0.25f * (sh[f1] + sh[128 + f1] + sh[256 + f1] + sh[384 + f1]) + bias[f1];
    if (act) { w0 = tanhf(w0); w1 = tanhf(w1); }
    else     { w0 = fmaxf(w0, 0.f); w1 = fmaxf(w1, 0.f); }
    if (z32) {
      z32[(size_t)n * F_ + f0] = w0;
      z32[(size_t)n * F_ + f1] = w1;
    }
    *(unsigned int*)&xout[(size_t)n * F_ + f0] = f2b2(w0, w1);
  }
}

// ---------------- launch ----------------
extern "C" void kernel_launch(void* const* d_in, const int* in_sizes, int n_in,
                              void* d_out, int out_size, void* d_ws, size_t ws_size,
                              hipStream_t stream) {
  const float* x = (const float*)d_in[0];
  const int* ei = (const int*)d_in[1];
  const float* W[4]; const float* asv[4]; const float* adv[4]; const float* bv[4];
  for (int i = 0; i < 4; ++i) {
    W[i]   = (const float*)d_in[2 + i * 4];
    asv[i] = (const float*)d_in[3 + i * 4];
    adv[i] = (const float*)d_in[4 + i * 4];
    bv[i]  = (const float*)d_in[5 + i * 4];
  }
  float* out_adj = (float*)d_out;
  float* out_z = out_adj + (size_t)N_ * N_;

  char* w = (char*)d_ws;
  size_t o = 0;
  auto carve = [&](size_t bytes) {
    char* p = w + o;
    o += (bytes + 255) & ~(size_t)255;
    return p;
  };
  float* hbuf = (float*)carve((size_t)N_ * HF_ * 4);
  u16* h2   = (u16*)carve((size_t)N_ * HF_ * 2);
  u16* wt0  = (u16*)carve((size_t)HF_ * N_ * 2);
  u16* wt1  = (u16*)carve((size_t)HF_ * F_ * 2);
  u16* wt2  = (u16*)carve((size_t)HF_ * F_ * 2);
  u16* wt3  = (u16*)carve((size_t)HF_ * F_ * 2);
  float* als = (float*)carve((size_t)N_ * 4 * 4);
  float* ald = (float*)carve((size_t)N_ * 4 * 4);
  u16* bufA = (u16*)carve((size_t)N_ * F_ * 2);
  u16* bufB = (u16*)carve((size_t)N_ * F_ * 2);
  u16* zb   = (u16*)carve((size_t)N_ * F_ * 2);
  int* cnt = (int*)carve((size_t)2 * N_ * 4);  // cnt + fill
  int* fl = cnt + N_;
  int* rowptr = (int*)carve((size_t)(N_ + 1) * 4);
  int* csrc = (int*)carve((size_t)EN_ * 4);

  // Split-K partial buffer for layer-0 GEMM lives in out_adj (400 MB, dead
  // until the final decode GEMM): 8 slices x N*HF fp32 = 163.8 MB.
  const int SPLITK = 8;
  float* part = out_adj;

  dim3 tb(32, 8);
  transpose_f2b<<<dim3(16, 313), tb, 0, stream>>>(W[0], wt0, N_, HF_);
  transpose_f2b<<<dim3(16, 4), tb, 0, stream>>>(W[1], wt1, F_, HF_);
  transpose_f2b<<<dim3(16, 4), tb, 0, stream>>>(W[2], wt2, F_, HF_);
  transpose_f2b<<<dim3(16, 4), tb, 0, stream>>>(W[3], wt3, F_, HF_);

  zero_k<<<(2 * N_ + 255) / 256, 256, 0, stream>>>(cnt, 2 * N_);
  hist_k<<<(EN_ + 255) / 256, 256, 0, stream>>>(ei, cnt);
  scan_k<<<1, 1024, 0, stream>>>(cnt, rowptr);
  fill_k<<<(EN_ + 255) / 256, 256, 0, stream>>>(ei, rowptr, fl, csrc);

  const u16* wt[4] = {wt0, wt1, wt2, wt3};
  const u16* xin[4] = {nullptr, bufA, bufB, bufA};
  u16* xout[4] = {bufA, bufB, bufA, zb};

  for (int l = 0; l < 4; ++l) {
    if (l == 0) {
      gemm_k<1, 0, 1><<<dim3(4, 79, SPLITK), 256, 0, stream>>>(x, wt0, part,
                                                               N_, HF_, N_);
      prep_k<<<N_ / 4, 256, 0, stream>>>(part, asv[0], adv[0], h2, als, ald,
                                         SPLITK, (size_t)N_ * HF_);
    } else {
      gemm_k<0, 0, 0><<<dim3(4, 79), 256, 0, stream>>>(xin[l], wt[l], hbuf,
                                                       N_, HF_, F_);
      prep_k<<<N_ / 4, 256, 0, stream>>>(hbuf, asv[l], adv[l], h2, als, ald,
                                         1, 0);
    }
    agg_k<<<N_, 256, 0, stream>>>(h2, als, ald, rowptr, csrc, bv[l], xout[l],
                                  (l == 3) ? out_z : nullptr, (l == 3) ? 1 : 0);
  }

  gemm_k<0, 1, 0><<<dim3(79, 79), 256, 0, stream>>>(zb, zb, out_adj, N_, N_, F_);
}

// Round 6
// 1282.486 us; speedup vs baseline: 1.0907x; 1.0907x over previous
//
#include <hip/hip_runtime.h>

#define N_ 10000
#define H_ 4
#define F_ 128
#define HF_ 512
#define E_ 320000
#define EN_ 330000  // E + N self loops

typedef unsigned short u16;
typedef __attribute__((ext_vector_type(8))) short bf16x8;
typedef __attribute__((ext_vector_type(4))) float f32x4;

__device__ __forceinline__ u16 f2b1(float f) {
  return (u16)((__float_as_uint(f) + 0x8000u) >> 16);
}
__device__ __forceinline__ unsigned int f2b2(float a, float b) {
  unsigned int ua = __float_as_uint(a) + 0x8000u;
  unsigned int ub = __float_as_uint(b) + 0x8000u;
  return (ua >> 16) | (ub & 0xffff0000u);
}
__device__ __forceinline__ float b2f(u16 u) {
  return __uint_as_float(((unsigned int)u) << 16);
}
__device__ __forceinline__ void async_cp16(const void* g, void* l) {
  __builtin_amdgcn_global_load_lds((__attribute__((address_space(1))) void*)g,
                                   (__attribute__((address_space(3))) void*)l,
                                   16, 0, 0);
}

// ---------------- transpose + convert: out_bf16[c][r] = in_f32[r][c] ----------------
__global__ void transpose_f2b(const float* __restrict__ in, u16* __restrict__ out,
                              int R, int C) {
  __shared__ float t[32][33];
  int bx = blockIdx.x * 32, by = blockIdx.y * 32;
  int tx = threadIdx.x, ty = threadIdx.y;  // 32 x 8
#pragma unroll
  for (int i = 0; i < 32; i += 8) {
    int r = by + ty + i, c = bx + tx;
    if (r < R && c < C) t[ty + i][tx] = in[(size_t)r * C + c];
  }
  __syncthreads();
#pragma unroll
  for (int i = 0; i < 32; i += 8) {
    int c = bx + ty + i, r = by + tx;
    if (r < R && c < C) out[(size_t)c * R + r] = f2b1(t[tx][ty + i]);
  }
}

// ---------------- CSR build ----------------
__global__ void zero_k(int* __restrict__ p, int n) {
  int t = blockIdx.x * blockDim.x + threadIdx.x;
  if (t < n) p[t] = 0;
}
__global__ void hist_k(const int* __restrict__ ei, int* __restrict__ cnt) {
  int t = blockIdx.x * blockDim.x + threadIdx.x;
  if (t >= EN_) return;
  int d = (t < E_) ? ei[E_ + t] : (t - E_);
  atomicAdd(&cnt[d], 1);
}
__global__ void scan_k(const int* __restrict__ cnt, int* __restrict__ rp) {
  __shared__ int l[1024];
  const int CH = 10;
  int t = threadIdx.x;
  int base = t * CH;
  int loc[CH];
  int s = 0;
#pragma unroll
  for (int i = 0; i < CH; ++i) {
    int idx = base + i;
    int c = (idx < N_) ? cnt[idx] : 0;
    loc[i] = s; s += c;
  }
  l[t] = s;
  __syncthreads();
  for (int off = 1; off < 1024; off <<= 1) {
    int v = (t >= off) ? l[t - off] : 0;
    __syncthreads();
    l[t] += v;
    __syncthreads();
  }
  int cb = (t == 0) ? 0 : l[t - 1];
#pragma unroll
  for (int i = 0; i < CH; ++i) {
    int idx = base + i;
    if (idx < N_) rp[idx] = cb + loc[i];
  }
  if (t == 1023) rp[N_] = l[1023];
}
__global__ void fill_k(const int* __restrict__ ei, const int* __restrict__ rp,
                       int* __restrict__ fl, int* __restrict__ csrc) {
  int t = blockIdx.x * blockDim.x + threadIdx.x;
  if (t >= EN_) return;
  int s, d;
  if (t < E_) { s = ei[t]; d = ei[E_ + t]; } else { s = d = t - E_; }
  int pos = rp[d] + atomicAdd(&fl[d], 1);
  csrc[pos] = s;
}

// ---------------- MFMA GEMM: C[M,Nc] = A[M,K] * Bt[Nc,K]^T ----------------
// R4-best config: BK=32, 2-barrier loop, XCD-pinned split-K (z = flat%8).
// ASRC 0: A is bf16 (async staging). ASRC 1: A is fp32 (fused convert staging).
// MODE 0: plain fp32 store. MODE 1: sigmoid fp32 store.
#define MFMA_STEP()                                                           \
  {                                                                           \
    bf16x8 af[4], bv[4];                                                      \
    _Pragma("unroll") for (int i = 0; i < 4; ++i)                             \
        af[i] = *(const bf16x8*)&As[(wm + i * 16 + l16) * 32 + quad * 8];     \
    _Pragma("unroll") for (int j = 0; j < 4; ++j)                             \
        bv[j] = *(const bf16x8*)&Bs[(wn + j * 16 + l16) * 32 + quad * 8];     \
    _Pragma("unroll") for (int i = 0; i < 4; ++i)                             \
        _Pragma("unroll") for (int j = 0; j < 4; ++j)                         \
            acc[i][j] = __builtin_amdgcn_mfma_f32_16x16x32_bf16(              \
                af[i], bv[j], acc[i][j], 0, 0, 0);                            \
  }

template <int ASRC, int MODE, int SPLIT>
__global__ __launch_bounds__(256) void gemm_k(const void* __restrict__ Av,
                                              const u16* __restrict__ Bt,
                                              float* __restrict__ C,
                                              int M, int Nc, int K) {
  __shared__ u16 As[128 * 32];
  __shared__ u16 Bs[128 * 32];
  const int tid = threadIdx.x;
  const int lane = tid & 63, wave = tid >> 6;
  const int wm = (wave >> 1) * 64, wn = (wave & 1) * 64;
  const int l16 = lane & 15, quad = lane >> 4;
  const int r0 = tid >> 2, kk = (tid & 3) * 8;

  int xb = blockIdx.x, yb = blockIdx.y, zb = 0;
  if (SPLIT) {
    int flat = blockIdx.x + gridDim.x * (blockIdx.y + gridDim.y * blockIdx.z);
    zb = flat % (int)gridDim.z;
    int r = flat / (int)gridDim.z;
    xb = r % (int)gridDim.x;
    yb = r / (int)gridDim.x;
  }
  const int mBase = yb * 128, nBase = xb * 128;

  int k0 = 0, k1 = K;
  if (SPLIT) {
    int Kper = ((K + (int)gridDim.z - 1) / (int)gridDim.z + 31) & ~31;
    k0 = zb * Kper;
    k1 = min(K, k0 + Kper);
    if (k0 > k1) k0 = k1;
  }
  const int len = k1 - k0;

  const u16* Ab = (const u16*)Av;
  const float* Af = (const float*)Av;

  size_t ar0 = (size_t)min(mBase + r0, M - 1);
  size_t ar1 = (size_t)min(mBase + r0 + 64, M - 1);
  size_t br0 = (size_t)min(nBase + r0, Nc - 1);
  size_t br1 = (size_t)min(nBase + r0 + 64, Nc - 1);
  const u16* pb0 = Bt + br0 * (size_t)K + k0 + kk;
  const u16* pb1 = Bt + br1 * (size_t)K + k0 + kk;
  const u16* pa0 = Ab + ar0 * (size_t)K + k0 + kk;
  const u16* pa1 = Ab + ar1 * (size_t)K + k0 + kk;
  const float* pf0 = Af + ar0 * (size_t)K + k0 + kk;
  const float* pf1 = Af + ar1 * (size_t)K + k0 + kk;
  u16* lA0 = As + wave * 512;
  u16* lA1 = As + 2048 + wave * 512;
  u16* lB0 = Bs + wave * 512;
  u16* lB1 = Bs + 2048 + wave * 512;

  f32x4 acc[4][4];
  f32x4 zr = {0.f, 0.f, 0.f, 0.f};
#pragma unroll
  for (int i = 0; i < 4; ++i)
#pragma unroll
    for (int j = 0; j < 4; ++j) acc[i][j] = zr;

  const int Lmain = len & ~31;
  for (int kb = 0; kb < Lmain; kb += 32) {
    async_cp16(pb0 + kb, lB0);
    async_cp16(pb1 + kb, lB1);
    if (ASRC == 0) {
      async_cp16(pa0 + kb, lA0);
      async_cp16(pa1 + kb, lA1);
    } else {
      float4 x0 = *(const float4*)(pf0 + kb);
      float4 x1 = *(const float4*)(pf0 + kb + 4);
      float4 x2 = *(const float4*)(pf1 + kb);
      float4 x3 = *(const float4*)(pf1 + kb + 4);
      uint4 u0 = make_uint4(f2b2(x0.x, x0.y), f2b2(x0.z, x0.w),
                            f2b2(x1.x, x1.y), f2b2(x1.z, x1.w));
      uint4 u1 = make_uint4(f2b2(x2.x, x2.y), f2b2(x2.z, x2.w),
                            f2b2(x3.x, x3.y), f2b2(x3.z, x3.w));
      *(uint4*)&As[r0 * 32 + kk] = u0;
      *(uint4*)&As[(r0 + 64) * 32 + kk] = u1;
    }
    __syncthreads();
    MFMA_STEP();
    __syncthreads();
  }
  if (len & 31) {
#pragma unroll
    for (int c = 0; c < 2; ++c) {
      size_t gr = c ? ar1 : ar0;
      size_t gb = c ? br1 : br0;
      int lrow = r0 + c * 64;
#pragma unroll
      for (int j = 0; j < 8; ++j) {
        int k = k0 + Lmain + kk + j;
        u16 av = 0, bvv = 0;
        if (k < k1) {
          av = (ASRC == 1) ? f2b1(Af[gr * (size_t)K + k]) : Ab[gr * (size_t)K + k];
          bvv = Bt[gb * (size_t)K + k];
        }
        As[lrow * 32 + kk + j] = av;
        Bs[lrow * 32 + kk + j] = bvv;
      }
    }
    __syncthreads();
    MFMA_STEP();
  }

  float* Cw = SPLIT ? (C + (size_t)zb * (size_t)M * (size_t)Nc) : C;
#pragma unroll
  for (int i = 0; i < 4; ++i)
#pragma unroll
    for (int j = 0; j < 4; ++j)
#pragma unroll
      for (int r = 0; r < 4; ++r) {
        int row = mBase + wm + i * 16 + quad * 4 + r;
        int col = nBase + wn + j * 16 + l16;
        if (row < M && col < Nc) {
          float v = acc[i][j][r];
          if (!SPLIT && MODE == 1) v = 1.f / (1.f + __expf(-v));
          Cw[(size_t)row * Nc + col] = v;
        }
      }
}

// ---------------- prep: h fp32 (sum of S partials) -> h bf16, attention logits ----------------
__global__ __launch_bounds__(256) void prep_k(const float* __restrict__ h,
                                              const float* __restrict__ asv,
                                              const float* __restrict__ adv,
                                              u16* __restrict__ h2,
                                              float* __restrict__ als,
                                              float* __restrict__ ald,
                                              int S, size_t zstride) {
  int wave = threadIdx.x >> 6, lane = threadIdx.x & 63;
  int node = blockIdx.x * 4 + wave;
  if (node >= N_) return;
  const float* hp = h + (size_t)node * HF_;
  float4 v0 = ((const float4*)hp)[lane * 2];
  float4 v1 = ((const float4*)hp)[lane * 2 + 1];
#pragma unroll 1
  for (int z = 1; z < S; ++z) {
    const float* pp = hp + (size_t)z * zstride;
    float4 w0 = ((const float4*)pp)[lane * 2];
    float4 w1 = ((const float4*)pp)[lane * 2 + 1];
    v0.x += w0.x; v0.y += w0.y; v0.z += w0.z; v0.w += w0.w;
    v1.x += w1.x; v1.y += w1.y; v1.z += w1.z; v1.w += w1.w;
  }
  float vv[8] = {v0.x, v0.y, v0.z, v0.w, v1.x, v1.y, v1.z, v1.w};
  uint4 pk = make_uint4(f2b2(vv[0], vv[1]), f2b2(vv[2], vv[3]),
                        f2b2(vv[4], vv[5]), f2b2(vv[6], vv[7]));
  *(uint4*)&h2[(size_t)node * HF_ + lane * 8] = pk;
  float4 a0 = ((const float4*)(asv + lane * 8))[0];
  float4 a1 = ((const float4*)(asv + lane * 8))[1];
  float4 d0 = ((const float4*)(adv + lane * 8))[0];
  float4 d1 = ((const float4*)(adv + lane * 8))[1];
  float aa[8] = {a0.x, a0.y, a0.z, a0.w, a1.x, a1.y, a1.z, a1.w};
  float dd[8] = {d0.x, d0.y, d0.z, d0.w, d1.x, d1.y, d1.z, d1.w};
  float ss = 0.f, sd = 0.f;
#pragma unroll
  for (int j = 0; j < 8; ++j) {
    ss += vv[j] * aa[j];
    sd += vv[j] * dd[j];
  }
#pragma unroll
  for (int m = 1; m <= 8; m <<= 1) {
    ss += __shfl_xor(ss, m, 64);
    sd += __shfl_xor(sd, m, 64);
  }
  if ((lane & 15) == 0) {
    int hh = lane >> 4;
    als[node * 4 + hh] = ss;
    ald[node * 4 + hh] = sd;
  }
}

// ---------------- aggregate: WAVE-per-node softmax attention + head-mean + act ----
// One 64-lane wave per node (4 nodes/block). No LDS, no __syncthreads.
// Phase A: lane-strided max over edges, 6-step shfl_xor reduce (4 heads).
// Phase B: serial edge loop; lane owns 8 contiguous features (16B h2 loads);
//          head = lane>>4; ssum per-lane (identical within head group).
// Epilogue: head-mean via shfl_xor(16)+shfl_xor(32); lanes 0-15 store 128 f.
__global__ __launch_bounds__(256) void agg_k(const u16* __restrict__ h2,
                                             const float* __restrict__ als,
                                             const float* __restrict__ ald,
                                             const int* __restrict__ rp,
                                             const int* __restrict__ csrc,
                                             const float* __restrict__ bias,
                                             u16* __restrict__ xout,
                                             float* __restrict__ z32, int act) {
  int wave = threadIdx.x >> 6, lane = threadIdx.x & 63;
  int n = blockIdx.x * 4 + wave;
  if (n >= N_) return;
  int start = rp[n], end = rp[n + 1];
  int hh = lane >> 4;

  float4 ad4 = *(const float4*)&ald[n * 4];
  float adh[4] = {ad4.x, ad4.y, ad4.z, ad4.w};

  // Phase A: per-head max over incoming edges
  float lm[4] = {-1e30f, -1e30f, -1e30f, -1e30f};
  for (int j = start + lane; j < end; j += 64) {
    int s = csrc[j];
    float4 a4 = *(const float4*)&als[s * 4];
    float e0 = a4.x + adh[0]; e0 = e0 > 0.f ? e0 : 0.2f * e0;
    float e1 = a4.y + adh[1]; e1 = e1 > 0.f ? e1 : 0.2f * e1;
    float e2 = a4.z + adh[2]; e2 = e2 > 0.f ? e2 : 0.2f * e2;
    float e3 = a4.w + adh[3]; e3 = e3 > 0.f ? e3 : 0.2f * e3;
    lm[0] = fmaxf(lm[0], e0); lm[1] = fmaxf(lm[1], e1);
    lm[2] = fmaxf(lm[2], e2); lm[3] = fmaxf(lm[3], e3);
  }
#pragma unroll
  for (int m = 1; m <= 32; m <<= 1) {
#pragma unroll
    for (int h = 0; h < 4; ++h) lm[h] = fmaxf(lm[h], __shfl_xor(lm[h], m, 64));
  }
  float mh = lm[hh];
  float adhh = adh[hh];

  // Phase B: weighted feature accumulation; lane owns elems [lane*8, lane*8+8)
  float acc[8] = {0.f, 0.f, 0.f, 0.f, 0.f, 0.f, 0.f, 0.f};
  float ssum = 0.f;
  const u16* hrow = h2 + (size_t)lane * 8;
  for (int j = start; j < end; ++j) {
    int s = csrc[j];
    float e = als[s * 4 + hh] + adhh;
    e = e > 0.f ? e : 0.2f * e;
    float w = __expf(e - mh);
    ssum += w;
    bf16x8 pv = *(const bf16x8*)(hrow + (size_t)s * HF_);
#pragma unroll
    for (int k = 0; k < 8; ++k) acc[k] += w * b2f((u16)pv[k]);
  }
  float inv = 1.f / ssum;
#pragma unroll
  for (int k = 0; k < 8; ++k) acc[k] *= inv;

  // Epilogue: mean over 4 heads (lanes 16 apart hold same f, different head)
#pragma unroll
  for (int k = 0; k < 8; ++k) {
    acc[k] += __shfl_xor(acc[k], 16, 64);
    acc[k] += __shfl_xor(acc[k], 32, 64);
  }
  if (lane < 16) {
    int f0 = lane * 8;
    float4 b0 = *(const float4*)(bias + f0);
    float4 b1 = *(const float4*)(bias + f0 + 4);
    float bb[8] = {b0.x, b0.y, b0.z, b0.w, b1.x, b1.y, b1.z, b1.w};
    float wv[8];
#pragma unroll
    for (int k = 0; k < 8; ++k) {
      float v = 0.25f * acc[k] + bb[k];
      wv[k] = act ? tanhf(v) : fmaxf(v, 0.f);
    }
    if (z32) {
      float4 z0 = {wv[0], wv[1], wv[2], wv[3]};
      float4 z1 = {wv[4], wv[5], wv[6], wv[7]};
      *(float4*)&z32[(size_t)n * F_ + f0] = z0;
      *(float4*)&z32[(size_t)n * F_ + f0 + 4] = z1;
    }
    uint4 pk = make_uint4(f2b2(wv[0], wv[1]), f2b2(wv[2], wv[3]),
                          f2b2(wv[4], wv[5]), f2b2(wv[6], wv[7]));
    *(uint4*)&xout[(size_t)n * F_ + f0] = pk;
  }
}

// ---------------- launch ----------------
extern "C" void kernel_launch(void* const* d_in, const int* in_sizes, int n_in,
                              void* d_out, int out_size, void* d_ws, size_t ws_size,
                              hipStream_t stream) {
  const float* x = (const float*)d_in[0];
  const int* ei = (const int*)d_in[1];
  const float* W[4]; const float* asv[4]; const float* adv[4]; const float* bv[4];
  for (int i = 0; i < 4; ++i) {
    W[i]   = (const float*)d_in[2 + i * 4];
    asv[i] = (const float*)d_in[3 + i * 4];
    adv[i] = (const float*)d_in[4 + i * 4];
    bv[i]  = (const float*)d_in[5 + i * 4];
  }
  float* out_adj = (float*)d_out;
  float* out_z = out_adj + (size_t)N_ * N_;

  char* w = (char*)d_ws;
  size_t o = 0;
  auto carve = [&](size_t bytes) {
    char* p = w + o;
    o += (bytes + 255) & ~(size_t)255;
    return p;
  };
  float* hbuf = (float*)carve((size_t)N_ * HF_ * 4);
  u16* h2   = (u16*)carve((size_t)N_ * HF_ * 2);
  u16* wt0  = (u16*)carve((size_t)HF_ * N_ * 2);
  u16* wt1  = (u16*)carve((size_t)HF_ * F_ * 2);
  u16* wt2  = (u16*)carve((size_t)HF_ * F_ * 2);
  u16* wt3  = (u16*)carve((size_t)HF_ * F_ * 2);
  float* als = (float*)carve((size_t)N_ * 4 * 4);
  float* ald = (float*)carve((size_t)N_ * 4 * 4);
  u16* bufA = (u16*)carve((size_t)N_ * F_ * 2);
  u16* bufB = (u16*)carve((size_t)N_ * F_ * 2);
  u16* zb   = (u16*)carve((size_t)N_ * F_ * 2);
  int* cnt = (int*)carve((size_t)2 * N_ * 4);  // cnt + fill
  int* fl = cnt + N_;
  int* rowptr = (int*)carve((size_t)(N_ + 1) * 4);
  int* csrc = (int*)carve((size_t)EN_ * 4);

  // Split-K partial buffer for layer-0 GEMM lives in out_adj (400 MB, dead
  // until the final decode GEMM): 8 slices x N*HF fp32 = 163.8 MB.
  const int SPLITK = 8;
  float* part = out_adj;

  dim3 tb(32, 8);
  transpose_f2b<<<dim3(16, 313), tb, 0, stream>>>(W[0], wt0, N_, HF_);
  transpose_f2b<<<dim3(16, 4), tb, 0, stream>>>(W[1], wt1, F_, HF_);
  transpose_f2b<<<dim3(16, 4), tb, 0, stream>>>(W[2], wt2, F_, HF_);
  transpose_f2b<<<dim3(16, 4), tb, 0, stream>>>(W[3], wt3, F_, HF_);

  zero_k<<<(2 * N_ + 255) / 256, 256, 0, stream>>>(cnt, 2 * N_);
  hist_k<<<(EN_ + 255) / 256, 256, 0, stream>>>(ei, cnt);
  scan_k<<<1, 1024, 0, stream>>>(cnt, rowptr);
  fill_k<<<(EN_ + 255) / 256, 256, 0, stream>>>(ei, rowptr, fl, csrc);

  const u16* wt[4] = {wt0, wt1, wt2, wt3};
  const u16* xin[4] = {nullptr, bufA, bufB, bufA};
  u16* xout[4] = {bufA, bufB, bufA, zb};

  for (int l = 0; l < 4; ++l) {
    if (l == 0) {
      gemm_k<1, 0, 1><<<dim3(4, 79, SPLITK), 256, 0, stream>>>(x, wt0, part,
                                                               N_, HF_, N_);
      prep_k<<<N_ / 4, 256, 0, stream>>>(part, asv[0], adv[0], h2, als, ald,
                                         SPLITK, (size_t)N_ * HF_);
    } else {
      gemm_k<0, 0, 0><<<dim3(4, 79), 256, 0, stream>>>(xin[l], wt[l], hbuf,
                                                       N_, HF_, F_);
      prep_k<<<N_ / 4, 256, 0, stream>>>(hbuf, asv[l], adv[l], h2, als, ald,
                                         1, 0);
    }
    agg_k<<<(N_ + 3) / 4, 256, 0, stream>>>(h2, als, ald, rowptr, csrc, bv[l],
                                            xout[l], (l == 3) ? out_z : nullptr,
                                            (l == 3) ? 1 : 0);
  }

  gemm_k<0, 1, 0><<<dim3(79, 79), 256, 0, stream>>>(zb, zb, out_adj, N_, N_, F_);
}